// Round 3
// baseline (237.094 us; speedup 1.0000x reference)
//
#include <hip/hip_runtime.h>

#define GX 432
#define GY 496
#define G_TOTAL (GX * GY) /* 214272, GZ=1 */
#define MAX_PTS 32
#define MAX_VOX 20000
#define CAP 64
#define NXCD 8
#define SEG_SH 10                 /* 1024 point-indices per segment */
#define NSEG ((2000000 >> SEG_SH) + 2) /* 1955: covers any n<=2e6+ */

typedef unsigned long long u64;

__device__ __forceinline__ int xcc_id() {
    int x;
    asm volatile("s_getreg_b32 %0, hwreg(HW_REG_XCC_ID)" : "=s"(x));
    return x & 7;
}

// IEEE float32 ops exactly matching the reference:
// c = floor((p - lo)/vs), lo = [0, -39.68, -3], vs = [.16,.16,4].
__device__ __forceinline__ int cell_of(float4 p, bool& ok) {
    float fx = floorf((p.x - 0.0f) / 0.16f);
    float fy = floorf((p.y + 39.68f) / 0.16f);
    float fz = floorf((p.z + 3.0f) / 4.0f);
    int cx = (int)fx, cy = (int)fy, cz = (int)fz;
    ok = (cx >= 0 && cx < GX && cy >= 0 && cy < GY && cz == 0);
    return cy * GX + cx;
}

// Pass 1: init small ws arrays; per point store cell id and do a
// load-filtered XCD-local atomicMin of the point index.
__global__ __launch_bounds__(256) void pass1(const float4* __restrict__ pts,
                                             int* __restrict__ lin,
                                             int* __restrict__ first8,
                                             u64* __restrict__ bitmap8,
                                             int* __restrict__ segCnt8,
                                             int* __restrict__ vcount,
                                             int* __restrict__ cellOfRank,
                                             int W, int n) {
    int i = blockIdx.x * 256 + threadIdx.x;
    // fused inits (complete before any consumer kernel starts)
    if (i < NXCD * W) bitmap8[i] = 0ull;
    if (i < NXCD * NSEG) segCnt8[i] = 0;
    if (i < MAX_VOX) { vcount[i] = -1; cellOfRank[i] = -1; }
    if (i >= n) return;
    float4 p = pts[i];
    bool ok;
    int c = cell_of(p, ok);
    lin[i] = ok ? c : -1;
    if (ok) {
        int* dst = first8 + (size_t)xcc_id() * G_TOTAL + c;
        // plain-load filter: stale values can only be too HIGH (monotone
        // decreasing), so a skipped atomic is always safe.
        if (*(volatile int*)dst > i) {
            __hip_atomic_fetch_min(dst, i, __ATOMIC_RELAXED,
                                   __HIP_MEMORY_SCOPE_WORKGROUP);
        }
    }
}

// Merge 8 first copies; mark first-point bitmap + per-segment histogram
// (both XCD-local copies, workgroup-scope RMW stays in the local L2).
__global__ __launch_bounds__(256) void mergeMark(const int* __restrict__ first8,
                                                 int* __restrict__ first,
                                                 u64* __restrict__ bitmap8,
                                                 int* __restrict__ segCnt8,
                                                 int W, int n) {
    int c = blockIdx.x * 256 + threadIdx.x;
    if (c >= G_TOTAL) return;
    int f = first8[c];
#pragma unroll
    for (int k = 1; k < NXCD; k++) f = min(f, first8[(size_t)k * G_TOTAL + c]);
    first[c] = f;
    if (f < n) {
        int x = xcc_id();
        __hip_atomic_fetch_or(bitmap8 + (size_t)x * W + (f >> 6),
                              1ull << (f & 63), __ATOMIC_RELAXED,
                              __HIP_MEMORY_SCOPE_WORKGROUP);
        __hip_atomic_fetch_add(segCnt8 + (size_t)x * NSEG + (f >> SEG_SH), 1,
                               __ATOMIC_RELAXED, __HIP_MEMORY_SCOPE_WORKGROUP);
    }
}

// Single-block scan: merge 8 segment histograms, exclusive-scan 1955
// segments, emit num_voxels.
__global__ __launch_bounds__(1024) void kScan(const int* __restrict__ segCnt8,
                                              int* __restrict__ segExcl,
                                              float* __restrict__ nvOut) {
    __shared__ int wsum[16], wexc[16];
    int t = threadIdx.x;
    int i0 = 2 * t, i1 = 2 * t + 1;
    int s0 = 0, s1 = 0;
    if (i0 < NSEG) {
#pragma unroll
        for (int k = 0; k < NXCD; k++) s0 += segCnt8[(size_t)k * NSEG + i0];
    }
    if (i1 < NSEG) {
#pragma unroll
        for (int k = 0; k < NXCD; k++) s1 += segCnt8[(size_t)k * NSEG + i1];
    }
    int tot = s0 + s1;
    int lane = t & 63, w = t >> 6;
    int x = tot;
    for (int d = 1; d < 64; d <<= 1) {
        int y = __shfl_up(x, d, 64);
        if (lane >= d) x += y;
    }
    if (lane == 63) wsum[w] = x;
    __syncthreads();
    if (t == 0) {
        int a = 0;
        for (int j = 0; j < 16; j++) { wexc[j] = a; a += wsum[j]; }
        nvOut[0] = (float)(a < MAX_VOX ? a : MAX_VOX);
    }
    __syncthreads();
    int excl = wexc[w] + x - tot;
    if (i0 < NSEG) segExcl[i0] = excl;
    if (i1 < NSEG) segExcl[i1] = excl + s0;
}

// Rank each nonempty cell: segment base + popcount of merged bitmap words
// before its first-index within the segment.
__global__ __launch_bounds__(256) void rankCells(const int* __restrict__ first,
                                                 const u64* __restrict__ bitmap8,
                                                 const int* __restrict__ segExcl,
                                                 int* __restrict__ rank,
                                                 int* __restrict__ cellOfRank,
                                                 int W, int n) {
    int c = blockIdx.x * 256 + threadIdx.x;
    if (c >= G_TOTAL) return;
    int f = first[c];
    if (f >= n) return;
    int seg = f >> SEG_SH;
    int wf = f >> 6;
    int cnt = 0;
    for (int w = seg << (SEG_SH - 6); w < wf; w++) {
        u64 m = 0;
#pragma unroll
        for (int k = 0; k < NXCD; k++) m |= bitmap8[(size_t)k * W + w];
        cnt += __popcll(m);
    }
    u64 mw = 0;
#pragma unroll
    for (int k = 0; k < NXCD; k++) mw |= bitmap8[(size_t)k * W + wf];
    int b = f & 63;
    cnt += __popcll(mw & ((b == 0) ? 0ull : ((~0ull) >> (64 - b))));
    int vr = segExcl[seg] + cnt;
    rank[c] = vr;
    if (vr < MAX_VOX) cellOfRank[vr] = c;
}

// Pass 5: append point indices into kept voxels' lists.
// vcount starts at -1; atomicAdd returns old, pos = old+1.
__global__ __launch_bounds__(256) void pass5(const int* __restrict__ lin,
                                             const int* __restrict__ rank,
                                             int* __restrict__ vcount,
                                             int* __restrict__ list, int n) {
    int i = blockIdx.x * 256 + threadIdx.x;
    if (i >= n) return;
    int c = lin[i];
    if (c < 0) return;
    int vr = rank[c];
    if (vr >= MAX_VOX) return;
    int pos = atomicAdd(&vcount[vr], 1) + 1;
    if (pos < CAP) list[vr * CAP + pos] = i;
}

// Pass F: 4 voxels per 256-thread block (one wave each). Counting-sort the
// collected indices (LDS broadcast reads), write all 32 slots + num_points
// + coors (so no d_out pre-memset is needed).
__global__ __launch_bounds__(256) void passF(const float4* __restrict__ pts,
                                             const int* __restrict__ vcount,
                                             const int* __restrict__ cellOfRank,
                                             const int* __restrict__ list,
                                             float4* __restrict__ voxOut,
                                             float* __restrict__ coorsOut,
                                             float* __restrict__ npOut) {
    __shared__ int s[4][CAP];
    __shared__ int slotPt[4][MAX_PTS];
    int w = threadIdx.x >> 6, lane = threadIdx.x & 63;
    int v = blockIdx.x * 4 + w;
    int cnt = vcount[v] + 1;
    int m = cnt < CAP ? cnt : CAP;
    s[w][lane] = (lane < m) ? list[v * CAP + lane] : 0x7FFFFFFF;
    if (lane < MAX_PTS) slotPt[w][lane] = -1;
    __syncthreads();
    int my = s[w][lane];
    int r = 0;
#pragma unroll
    for (int j = 0; j < CAP; j++) r += (s[w][j] < my) ? 1 : 0;  // broadcast
    if (lane < m && r < MAX_PTS) slotPt[w][r] = my;
    __syncthreads();
    if (lane < MAX_PTS) {
        int p = slotPt[w][lane];
        float4 val = make_float4(0.f, 0.f, 0.f, 0.f);
        if (p >= 0) val = pts[p];
        voxOut[(size_t)v * MAX_PTS + lane] = val;
    }
    if (lane == 0) {
        npOut[v] = (float)(cnt < MAX_PTS ? cnt : MAX_PTS);
        int cell = cellOfRank[v];
        if (cell < 0) {
            coorsOut[3 * v + 0] = -1.0f;
            coorsOut[3 * v + 1] = -1.0f;
            coorsOut[3 * v + 2] = -1.0f;
        } else {
            coorsOut[3 * v + 0] = 0.0f;  // cz (GZ==1)
            coorsOut[3 * v + 1] = (float)(cell / GX);
            coorsOut[3 * v + 2] = (float)(cell % GX);
        }
    }
}

extern "C" void kernel_launch(void* const* d_in, const int* in_sizes, int n_in,
                              void* d_out, int out_size, void* d_ws, size_t ws_size,
                              hipStream_t stream) {
    const float4* pts = (const float4*)d_in[0];
    int n = in_sizes[0] / 4;  // 2,000,000
    int W = (n + 63) >> 6;    // 31250 bitmap words

    char* ws = (char*)d_ws;
    size_t off = 0;
    auto alloc = [&](size_t bytes) -> void* {
        void* p = (void*)(ws + off);
        off = (off + bytes + 255) & ~(size_t)255;
        return p;
    };
    int* first8 = (int*)alloc((size_t)NXCD * G_TOTAL * 4);
    int* first = (int*)alloc((size_t)G_TOTAL * 4);
    int* lin = (int*)alloc((size_t)n * 4);
    u64* bitmap8 = (u64*)alloc((size_t)NXCD * W * 8);
    int* segCnt8 = (int*)alloc((size_t)NXCD * NSEG * 4);
    int* segExcl = (int*)alloc((size_t)NSEG * 4);
    int* rank = (int*)alloc((size_t)G_TOTAL * 4);
    int* vcount = (int*)alloc((size_t)MAX_VOX * 4);
    int* cellOfRank = (int*)alloc((size_t)MAX_VOX * 4);
    int* list = (int*)alloc((size_t)MAX_VOX * CAP * 4);
    (void)ws_size;

    float* out = (float*)d_out;
    float4* voxOut = (float4*)out;                          // 20000*32*4
    float* coorsOut = out + (size_t)MAX_VOX * MAX_PTS * 4;  // 20000*3
    float* npOut = coorsOut + (size_t)MAX_VOX * 3;          // 20000
    float* nvOut = npOut + MAX_VOX;                         // 1

    hipMemsetAsync(first8, 0x7F, (size_t)NXCD * G_TOTAL * 4, stream);  // INF

    int nbP = (n + 255) / 256;        // 7813
    int nbC = (G_TOTAL + 255) / 256;  // 837

    pass1<<<nbP, 256, 0, stream>>>(pts, lin, first8, bitmap8, segCnt8,
                                   vcount, cellOfRank, W, n);
    mergeMark<<<nbC, 256, 0, stream>>>(first8, first, bitmap8, segCnt8, W, n);
    kScan<<<1, 1024, 0, stream>>>(segCnt8, segExcl, nvOut);
    rankCells<<<nbC, 256, 0, stream>>>(first, bitmap8, segExcl, rank, cellOfRank, W, n);
    pass5<<<nbP, 256, 0, stream>>>(lin, rank, vcount, list, n);
    passF<<<MAX_VOX / 4, 256, 0, stream>>>(pts, vcount, cellOfRank, list,
                                           voxOut, coorsOut, npOut);
}

// Round 5
// 146.613 us; speedup vs baseline: 1.6171x; 1.6171x over previous
//
#include <hip/hip_runtime.h>

#define GX 432
#define GY 496
#define G_TOTAL (GX * GY) /* 214272, GZ=1 */
#define MAX_PTS 32
#define MAX_VOX 20000
#define CAP 64

typedef unsigned long long u64;

// IEEE float32 ops exactly matching the reference:
// c = floor((p - lo)/vs), lo = [0, -39.68, -3], vs = [.16,.16,4].
__device__ __forceinline__ int cell_of(float4 p, bool& ok) {
    float fx = floorf((p.x - 0.0f) / 0.16f);
    float fy = floorf((p.y + 39.68f) / 0.16f);
    float fz = floorf((p.z + 3.0f) / 4.0f);
    int cx = (int)fx, cy = (int)fy, cz = (int)fz;
    ok = (cx >= 0 && cx < GX && cy >= 0 && cy < GY && cz == 0);
    return cy * GX + cx;
}

// Pass 1: fused inits + per-point cell id store + device atomicMin of index.
__global__ __launch_bounds__(256) void pass1(const float4* __restrict__ pts,
                                             int* __restrict__ lin,
                                             int* __restrict__ first,
                                             u64* __restrict__ isFirst64,
                                             int* __restrict__ vcount,
                                             int* __restrict__ cellOfRank,
                                             int W, int n) {
    int i = blockIdx.x * 256 + threadIdx.x;
    // fused inits (consumed only by LATER kernels — kernel boundary orders them)
    if (i < W * 8) isFirst64[i] = 0ull;  // zero W*64 bytes of isFirst
    if (i < MAX_VOX) { vcount[i] = -1; cellOfRank[i] = -1; }
    if (i >= n) return;
    float4 p = pts[i];
    bool ok;
    int c = cell_of(p, ok);
    lin[i] = ok ? c : -1;
    if (ok) atomicMin(&first[c], i);
}

// Mark first-point bytes. Distinct cells have distinct first indices, so a
// plain byte store is race-free (byte stores are byte-granular in HW).
__global__ __launch_bounds__(256) void markFirst(const int* __restrict__ first,
                                                 unsigned char* __restrict__ isFirst,
                                                 int n) {
    int c = blockIdx.x * 256 + threadIdx.x;
    if (c >= G_TOTAL) return;
    int f = first[c];
    if (f >= 0 && f < n) isFirst[f] = 1;
}

// Scan A: pack isFirst bytes -> bits[], per-word intra-block exclusive prefix
// (wordLocal) and per-block sums. One thread per 64-bit word, 256 words/block.
__global__ __launch_bounds__(256) void kScanA(const u64* __restrict__ isFirst64,
                                              u64* __restrict__ bits,
                                              unsigned* __restrict__ wordLocal,
                                              int* __restrict__ sums, int W) {
    __shared__ int wsum[4], wexc[4];
    int t = threadIdx.x;
    int wi = blockIdx.x * 256 + t;
    u64 mask = 0;
    if (wi < W) {
        const u64* src = isFirst64 + (size_t)wi * 8;
#pragma unroll
        for (int j = 0; j < 8; j++) {
            u64 chunk = src[j];  // 8 bytes, each 0 or 1
            u64 m8 = (chunk * 0x0102040810204080ull) >> 56;  // gather LSBs
            mask |= m8 << (8 * j);
        }
        bits[wi] = mask;
    }
    int v = __popcll(mask);
    int lane = t & 63, w = t >> 6;
    int x = v;
    for (int d = 1; d < 64; d <<= 1) {
        int y = __shfl_up(x, d, 64);
        if (lane >= d) x += y;
    }
    if (lane == 63) wsum[w] = x;
    __syncthreads();
    if (t == 0) {
        int a = 0;
        for (int j = 0; j < 4; j++) { wexc[j] = a; a += wsum[j]; }
        sums[blockIdx.x] = a;
    }
    __syncthreads();
    if (wi < W) wordLocal[wi] = (unsigned)(wexc[w] + x - v);
}

// Scan B: exclusive scan of per-block sums (nb <= 128); writes num_voxels.
__global__ __launch_bounds__(128) void kScanB(int* __restrict__ sums, int nb,
                                              float* __restrict__ nvOut) {
    __shared__ int wsum[2], wexc[2];
    int t = threadIdx.x;
    int v = (t < nb) ? sums[t] : 0;
    int lane = t & 63, w = t >> 6;
    int x = v;
    for (int d = 1; d < 64; d <<= 1) {
        int y = __shfl_up(x, d, 64);
        if (lane >= d) x += y;
    }
    if (lane == 63) wsum[w] = x;
    __syncthreads();
    if (t == 0) {
        int a = 0;
        for (int j = 0; j < 2; j++) { wexc[j] = a; a += wsum[j]; }
        nvOut[0] = (float)(a < MAX_VOX ? a : MAX_VOX);
    }
    __syncthreads();
    if (t < nb) sums[t] = wexc[w] + x - v;
}

// Rank cells: O(1) per cell — block base + intra-block word prefix + bit pop.
__global__ __launch_bounds__(256) void rankCells(const int* __restrict__ first,
                                                 const u64* __restrict__ bits,
                                                 const unsigned* __restrict__ wordLocal,
                                                 const int* __restrict__ sumsExcl,
                                                 int* __restrict__ rank,
                                                 int* __restrict__ cellOfRank, int n) {
    int c = blockIdx.x * 256 + threadIdx.x;
    if (c >= G_TOTAL) return;
    int f = first[c];
    if (f < 0 || f >= n) return;
    int wf = f >> 6;
    int b = f & 63;
    u64 lowmask = (b == 0) ? 0ull : ((~0ull) >> (64 - b));
    int vr = sumsExcl[wf >> 8] + (int)wordLocal[wf] + __popcll(bits[wf] & lowmask);
    rank[c] = vr;
    if (vr < MAX_VOX) cellOfRank[vr] = c;
}

// Pass 5: append point indices into kept voxels' lists.
// vcount starts at -1; atomicAdd returns old, pos = old+1.
__global__ __launch_bounds__(256) void pass5(const int* __restrict__ lin,
                                             const int* __restrict__ rank,
                                             int* __restrict__ vcount,
                                             int* __restrict__ list, int n) {
    int i = blockIdx.x * 256 + threadIdx.x;
    if (i >= n) return;
    int c = lin[i];
    if (c < 0) return;
    int vr = rank[c];
    if (vr >= MAX_VOX) return;
    int pos = atomicAdd(&vcount[vr], 1) + 1;
    if (pos < CAP) list[vr * CAP + pos] = i;
}

// Pass F: 4 voxels per 256-thread block (one wave each). Counting-sort the
// collected indices (LDS broadcast reads), write all 32 slots + num_points
// + coors (so no d_out pre-memset is needed).
__global__ __launch_bounds__(256) void passF(const float4* __restrict__ pts,
                                             const int* __restrict__ vcount,
                                             const int* __restrict__ cellOfRank,
                                             const int* __restrict__ list,
                                             float4* __restrict__ voxOut,
                                             float* __restrict__ coorsOut,
                                             float* __restrict__ npOut) {
    __shared__ int s[4][CAP];
    __shared__ int slotPt[4][MAX_PTS];
    int w = threadIdx.x >> 6, lane = threadIdx.x & 63;
    int v = blockIdx.x * 4 + w;
    int cnt = vcount[v] + 1;
    int m = cnt < CAP ? cnt : CAP;
    s[w][lane] = (lane < m) ? list[v * CAP + lane] : 0x7FFFFFFF;
    if (lane < MAX_PTS) slotPt[w][lane] = -1;
    __syncthreads();
    int my = s[w][lane];
    int r = 0;
#pragma unroll
    for (int j = 0; j < CAP; j++) r += (s[w][j] < my) ? 1 : 0;  // broadcast
    if (lane < m && r < MAX_PTS) slotPt[w][r] = my;
    __syncthreads();
    if (lane < MAX_PTS) {
        int p = slotPt[w][lane];
        float4 val = make_float4(0.f, 0.f, 0.f, 0.f);
        if (p >= 0) val = pts[p];
        voxOut[(size_t)v * MAX_PTS + lane] = val;
    }
    if (lane == 0) {
        npOut[v] = (float)(cnt < MAX_PTS ? cnt : MAX_PTS);
        int cell = cellOfRank[v];
        if (cell < 0) {
            coorsOut[3 * v + 0] = -1.0f;
            coorsOut[3 * v + 1] = -1.0f;
            coorsOut[3 * v + 2] = -1.0f;
        } else {
            coorsOut[3 * v + 0] = 0.0f;  // cz (GZ==1)
            coorsOut[3 * v + 1] = (float)(cell / GX);
            coorsOut[3 * v + 2] = (float)(cell % GX);
        }
    }
}

extern "C" void kernel_launch(void* const* d_in, const int* in_sizes, int n_in,
                              void* d_out, int out_size, void* d_ws, size_t ws_size,
                              hipStream_t stream) {
    const float4* pts = (const float4*)d_in[0];
    int n = in_sizes[0] / 4;  // 2,000,000
    int W = (n + 63) >> 6;    // 31250 bitmap words

    char* ws = (char*)d_ws;
    size_t off = 0;
    auto alloc = [&](size_t bytes) -> void* {
        void* p = (void*)(ws + off);
        off = (off + bytes + 255) & ~(size_t)255;
        return p;
    };
    int* first = (int*)alloc((size_t)G_TOTAL * 4);
    int* lin = (int*)alloc((size_t)n * 4);
    u64* isFirst64 = (u64*)alloc((size_t)W * 8 * 8);     // W*64 bytes
    u64* bits = (u64*)alloc((size_t)W * 8);
    unsigned* wordLocal = (unsigned*)alloc((size_t)W * 4);
    int* sums = (int*)alloc(128 * 4);
    int* rank = (int*)alloc((size_t)G_TOTAL * 4);
    int* vcount = (int*)alloc((size_t)MAX_VOX * 4);
    int* cellOfRank = (int*)alloc((size_t)MAX_VOX * 4);
    int* list = (int*)alloc((size_t)MAX_VOX * CAP * 4);
    (void)ws_size;
    (void)n_in;
    (void)out_size;

    float* out = (float*)d_out;
    float4* voxOut = (float4*)out;                          // 20000*32*4
    float* coorsOut = out + (size_t)MAX_VOX * MAX_PTS * 4;  // 20000*3
    float* npOut = coorsOut + (size_t)MAX_VOX * 3;          // 20000
    float* nvOut = npOut + MAX_VOX;                         // 1

    hipMemsetAsync(first, 0x7F, (size_t)G_TOTAL * 4, stream);  // INF

    int nbP = (n + 255) / 256;        // 7813
    int nbC = (G_TOTAL + 255) / 256;  // 837
    int nbW = (W + 255) / 256;        // 123

    pass1<<<nbP, 256, 0, stream>>>(pts, lin, first, isFirst64, vcount,
                                   cellOfRank, W, n);
    markFirst<<<nbC, 256, 0, stream>>>(first, (unsigned char*)isFirst64, n);
    kScanA<<<nbW, 256, 0, stream>>>(isFirst64, bits, wordLocal, sums, W);
    kScanB<<<1, 128, 0, stream>>>(sums, nbW, nvOut);
    rankCells<<<nbC, 256, 0, stream>>>(first, bits, wordLocal, sums, rank,
                                       cellOfRank, n);
    pass5<<<nbP, 256, 0, stream>>>(lin, rank, vcount, list, n);
    passF<<<MAX_VOX / 4, 256, 0, stream>>>(pts, vcount, cellOfRank, list,
                                           voxOut, coorsOut, npOut);
}

// Round 7
// 141.973 us; speedup vs baseline: 1.6700x; 1.0327x over previous
//
#include <hip/hip_runtime.h>

#define GX 432
#define GY 496
#define G_TOTAL (GX * GY) /* 214272, GZ=1 */
#define MAX_PTS 32
#define MAX_VOX 20000
#define CAP 64

typedef unsigned long long u64;

// IEEE float32 ops exactly matching the reference:
// c = floor((p - lo)/vs), lo = [0, -39.68, -3], vs = [.16,.16,4].
__device__ __forceinline__ int cell_of(float4 p, bool& ok) {
    float fx = floorf((p.x - 0.0f) / 0.16f);
    float fy = floorf((p.y + 39.68f) / 0.16f);
    float fz = floorf((p.z + 3.0f) / 4.0f);
    int cx = (int)fx, cy = (int)fy, cz = (int)fz;
    ok = (cx >= 0 && cx < GX && cy >= 0 && cy < GY && cz == 0);
    return cy * GX + cx;
}

// Pass 1, chunk kernel over points [start,end).
// Filter predicate (chunks >0): do the atomic ONLY if the observed value is
// LARGER than i. Observing smaller-or-equal means a legitimate winner already
// claimed the cell (any value < i in first[] is a real point index, and ties
// are impossible). Observing a stale/too-high value (including INF) merely
// fails to skip — always safe, at any cache state. This is the corrected
// direction of the round-6 predicate (which wrongly skipped on ANY non-INF,
// racing against same-chunk writers with larger indices).
template <bool FIRST_CHUNK>
__global__ __launch_bounds__(256) void pass1chunk(const float4* __restrict__ pts,
                                                  int* __restrict__ lin,
                                                  int* __restrict__ first,
                                                  u64* __restrict__ isFirst64,
                                                  int* __restrict__ vcount,
                                                  int* __restrict__ cellOfRank,
                                                  int W, int start, int end) {
    int t = blockIdx.x * 256 + threadIdx.x;
    if (FIRST_CHUNK) {
        if (t < W * 8) isFirst64[t] = 0ull;  // zero W*64 bytes of isFirst
        if (t < MAX_VOX) { vcount[t] = -1; cellOfRank[t] = -1; }
    }
    int i = start + t;
    if (i >= end) return;
    float4 p = pts[i];
    bool ok;
    int c = cell_of(p, ok);
    lin[i] = ok ? c : -1;
    if (ok) {
        if (FIRST_CHUNK) {
            atomicMin(&first[c], i);   // all cells INF; filter would be pure latency
        } else {
            if (first[c] > i) atomicMin(&first[c], i);
        }
    }
}

// Mark first-point bytes. Distinct cells have distinct first indices, so a
// plain byte store is race-free (byte stores are byte-granular in HW).
__global__ __launch_bounds__(256) void markFirst(const int* __restrict__ first,
                                                 unsigned char* __restrict__ isFirst,
                                                 int n) {
    int c = blockIdx.x * 256 + threadIdx.x;
    if (c >= G_TOTAL) return;
    int f = first[c];
    if (f >= 0 && f < n) isFirst[f] = 1;
}

// Scan A: pack isFirst bytes -> bits[], per-word intra-block exclusive prefix
// (wordLocal) and per-block sums. One thread per 64-bit word, 256 words/block.
__global__ __launch_bounds__(256) void kScanA(const u64* __restrict__ isFirst64,
                                              u64* __restrict__ bits,
                                              unsigned* __restrict__ wordLocal,
                                              int* __restrict__ sums, int W) {
    __shared__ int wsum[4], wexc[4];
    int t = threadIdx.x;
    int wi = blockIdx.x * 256 + t;
    u64 mask = 0;
    if (wi < W) {
        const u64* src = isFirst64 + (size_t)wi * 8;
#pragma unroll
        for (int j = 0; j < 8; j++) {
            u64 chunk = src[j];  // 8 bytes, each 0 or 1
            u64 m8 = (chunk * 0x0102040810204080ull) >> 56;  // gather LSBs
            mask |= m8 << (8 * j);
        }
        bits[wi] = mask;
    }
    int v = __popcll(mask);
    int lane = t & 63, w = t >> 6;
    int x = v;
    for (int d = 1; d < 64; d <<= 1) {
        int y = __shfl_up(x, d, 64);
        if (lane >= d) x += y;
    }
    if (lane == 63) wsum[w] = x;
    __syncthreads();
    if (t == 0) {
        int a = 0;
        for (int j = 0; j < 4; j++) { wexc[j] = a; a += wsum[j]; }
        sums[blockIdx.x] = a;
    }
    __syncthreads();
    if (wi < W) wordLocal[wi] = (unsigned)(wexc[w] + x - v);
}

// Scan B: exclusive scan of per-block sums (nb <= 128); writes num_voxels.
__global__ __launch_bounds__(128) void kScanB(int* __restrict__ sums, int nb,
                                              float* __restrict__ nvOut) {
    __shared__ int wsum[2], wexc[2];
    int t = threadIdx.x;
    int v = (t < nb) ? sums[t] : 0;
    int lane = t & 63, w = t >> 6;
    int x = v;
    for (int d = 1; d < 64; d <<= 1) {
        int y = __shfl_up(x, d, 64);
        if (lane >= d) x += y;
    }
    if (lane == 63) wsum[w] = x;
    __syncthreads();
    if (t == 0) {
        int a = 0;
        for (int j = 0; j < 2; j++) { wexc[j] = a; a += wsum[j]; }
        nvOut[0] = (float)(a < MAX_VOX ? a : MAX_VOX);
    }
    __syncthreads();
    if (t < nb) sums[t] = wexc[w] + x - v;
}

// Rank cells: O(1) per cell — block base + intra-block word prefix + bit pop.
__global__ __launch_bounds__(256) void rankCells(const int* __restrict__ first,
                                                 const u64* __restrict__ bits,
                                                 const unsigned* __restrict__ wordLocal,
                                                 const int* __restrict__ sumsExcl,
                                                 int* __restrict__ rank,
                                                 int* __restrict__ cellOfRank, int n) {
    int c = blockIdx.x * 256 + threadIdx.x;
    if (c >= G_TOTAL) return;
    int f = first[c];
    if (f < 0 || f >= n) return;
    int wf = f >> 6;
    int b = f & 63;
    u64 lowmask = (b == 0) ? 0ull : ((~0ull) >> (64 - b));
    int vr = sumsExcl[wf >> 8] + (int)wordLocal[wf] + __popcll(bits[wf] & lowmask);
    rank[c] = vr;
    if (vr < MAX_VOX) cellOfRank[vr] = c;
}

// Pass 5: append point indices into kept voxels' lists.
// vcount starts at -1; atomicAdd returns old, pos = old+1.
__global__ __launch_bounds__(256) void pass5(const int* __restrict__ lin,
                                             const int* __restrict__ rank,
                                             int* __restrict__ vcount,
                                             int* __restrict__ list, int n) {
    int i = blockIdx.x * 256 + threadIdx.x;
    if (i >= n) return;
    int c = lin[i];
    if (c < 0) return;
    int vr = rank[c];
    if (vr >= MAX_VOX) return;
    int pos = atomicAdd(&vcount[vr], 1) + 1;
    if (pos < CAP) list[vr * CAP + pos] = i;
}

// Pass F: 4 voxels per 256-thread block (one wave each). Counting-sort the
// collected indices (LDS broadcast reads), write all 32 slots + num_points
// + coors (so no d_out pre-memset is needed).
__global__ __launch_bounds__(256) void passF(const float4* __restrict__ pts,
                                             const int* __restrict__ vcount,
                                             const int* __restrict__ cellOfRank,
                                             const int* __restrict__ list,
                                             float4* __restrict__ voxOut,
                                             float* __restrict__ coorsOut,
                                             float* __restrict__ npOut) {
    __shared__ int s[4][CAP];
    __shared__ int slotPt[4][MAX_PTS];
    int w = threadIdx.x >> 6, lane = threadIdx.x & 63;
    int v = blockIdx.x * 4 + w;
    int cnt = vcount[v] + 1;
    int m = cnt < CAP ? cnt : CAP;
    s[w][lane] = (lane < m) ? list[v * CAP + lane] : 0x7FFFFFFF;
    if (lane < MAX_PTS) slotPt[w][lane] = -1;
    __syncthreads();
    int my = s[w][lane];
    int r = 0;
#pragma unroll
    for (int j = 0; j < CAP; j++) r += (s[w][j] < my) ? 1 : 0;  // broadcast
    if (lane < m && r < MAX_PTS) slotPt[w][r] = my;
    __syncthreads();
    if (lane < MAX_PTS) {
        int p = slotPt[w][lane];
        float4 val = make_float4(0.f, 0.f, 0.f, 0.f);
        if (p >= 0) val = pts[p];
        voxOut[(size_t)v * MAX_PTS + lane] = val;
    }
    if (lane == 0) {
        npOut[v] = (float)(cnt < MAX_PTS ? cnt : MAX_PTS);
        int cell = cellOfRank[v];
        if (cell < 0) {
            coorsOut[3 * v + 0] = -1.0f;
            coorsOut[3 * v + 1] = -1.0f;
            coorsOut[3 * v + 2] = -1.0f;
        } else {
            coorsOut[3 * v + 0] = 0.0f;  // cz (GZ==1)
            coorsOut[3 * v + 1] = (float)(cell / GX);
            coorsOut[3 * v + 2] = (float)(cell % GX);
        }
    }
}

extern "C" void kernel_launch(void* const* d_in, const int* in_sizes, int n_in,
                              void* d_out, int out_size, void* d_ws, size_t ws_size,
                              hipStream_t stream) {
    const float4* pts = (const float4*)d_in[0];
    int n = in_sizes[0] / 4;  // 2,000,000
    int W = (n + 63) >> 6;    // 31250 bitmap words

    char* ws = (char*)d_ws;
    size_t off = 0;
    auto alloc = [&](size_t bytes) -> void* {
        void* p = (void*)(ws + off);
        off = (off + bytes + 255) & ~(size_t)255;
        return p;
    };
    int* first = (int*)alloc((size_t)G_TOTAL * 4);
    int* lin = (int*)alloc((size_t)n * 4);
    u64* isFirst64 = (u64*)alloc((size_t)W * 8 * 8);     // W*64 bytes
    u64* bits = (u64*)alloc((size_t)W * 8);
    unsigned* wordLocal = (unsigned*)alloc((size_t)W * 4);
    int* sums = (int*)alloc(128 * 4);
    int* rank = (int*)alloc((size_t)G_TOTAL * 4);
    int* vcount = (int*)alloc((size_t)MAX_VOX * 4);
    int* cellOfRank = (int*)alloc((size_t)MAX_VOX * 4);
    int* list = (int*)alloc((size_t)MAX_VOX * CAP * 4);
    (void)ws_size;
    (void)n_in;
    (void)out_size;

    float* out = (float*)d_out;
    float4* voxOut = (float4*)out;                          // 20000*32*4
    float* coorsOut = out + (size_t)MAX_VOX * MAX_PTS * 4;  // 20000*3
    float* npOut = coorsOut + (size_t)MAX_VOX * 3;          // 20000
    float* nvOut = npOut + MAX_VOX;                         // 1

    hipMemsetAsync(first, 0x7F, (size_t)G_TOTAL * 4, stream);  // INF

    int chunk = (n + 3) / 4;               // 500000
    int nbK = (chunk + 255) / 256;         // 1954
    int nbC = (G_TOTAL + 255) / 256;       // 837
    int nbW = (W + 255) / 256;             // 123
    int nbP = (n + 255) / 256;             // 7813

    pass1chunk<true><<<nbK, 256, 0, stream>>>(pts, lin, first, isFirst64,
                                              vcount, cellOfRank, W, 0,
                                              min(chunk, n));
    for (int k = 1; k < 4; k++) {
        int s0 = k * chunk;
        int s1 = min(s0 + chunk, n);
        if (s0 >= s1) continue;
        pass1chunk<false><<<nbK, 256, 0, stream>>>(pts, lin, first, isFirst64,
                                                   vcount, cellOfRank, W, s0, s1);
    }
    markFirst<<<nbC, 256, 0, stream>>>(first, (unsigned char*)isFirst64, n);
    kScanA<<<nbW, 256, 0, stream>>>(isFirst64, bits, wordLocal, sums, W);
    kScanB<<<1, 128, 0, stream>>>(sums, nbW, nvOut);
    rankCells<<<nbC, 256, 0, stream>>>(first, bits, wordLocal, sums, rank,
                                       cellOfRank, n);
    pass5<<<nbP, 256, 0, stream>>>(lin, rank, vcount, list, n);
    passF<<<MAX_VOX / 4, 256, 0, stream>>>(pts, vcount, cellOfRank, list,
                                           voxOut, coorsOut, npOut);
}

// Round 8
// 125.843 us; speedup vs baseline: 1.8840x; 1.1282x over previous
//
#include <hip/hip_runtime.h>

#define GX 432
#define GY 496
#define G_TOTAL (GX * GY) /* 214272, GZ=1 */
#define MAX_PTS 32
#define MAX_VOX 20000
#define CAP 64
#define INF_SENTINEL 0x7F7F7F7F
#define PREFIX_K 262144  /* ~133k in-range claims -> ~99k distinct cells >> 20000 */

typedef unsigned long long u64;

// IEEE float32 ops exactly matching the reference:
// c = floor((p - lo)/vs), lo = [0, -39.68, -3], vs = [.16,.16,4].
__device__ __forceinline__ int cell_of(float4 p, bool& ok) {
    float fx = floorf((p.x - 0.0f) / 0.16f);
    float fy = floorf((p.y + 39.68f) / 0.16f);
    float fz = floorf((p.z + 3.0f) / 4.0f);
    int cx = (int)fx, cy = (int)fy, cz = (int)fz;
    ok = (cx >= 0 && cx < GX && cy >= 0 && cy < GY && cz == 0);
    return cy * GX + cx;
}

// Pass 1 (single kernel): fused inits + lin[] store for ALL points + cell
// claim (atomicMin) ONLY for the prefix i < K. Cells whose true first point
// is >= K cannot have rank < MAX_VOX as long as the prefix contains >=
// MAX_VOX distinct cells (validated by countD; repaired by guard otherwise).
__global__ __launch_bounds__(256) void pass1(const float4* __restrict__ pts,
                                             int* __restrict__ lin,
                                             int* __restrict__ first,
                                             u64* __restrict__ isFirst64,
                                             int* __restrict__ vcount,
                                             int* __restrict__ cellOfRank,
                                             int* __restrict__ rank,
                                             int* __restrict__ dcount,
                                             int W, int K, int n) {
    int i = blockIdx.x * 256 + threadIdx.x;
    // fused inits (consumed only by LATER kernels)
    if (i < W * 8) isFirst64[i] = 0ull;  // zero W*64 bytes of isFirst
    if (i < MAX_VOX) { vcount[i] = -1; cellOfRank[i] = -1; }
    if (i < G_TOTAL) rank[i] = INF_SENTINEL;  // cells never ranked -> huge
    if (i == 0) *dcount = 0;
    if (i >= n) return;
    float4 p = pts[i];
    bool ok;
    int c = cell_of(p, ok);
    lin[i] = ok ? c : -1;
    if (ok && i < K) atomicMin(&first[c], i);
}

// Count distinct cells claimed by the prefix.
__global__ __launch_bounds__(256) void countD(const int* __restrict__ first,
                                              int* __restrict__ dcount) {
    __shared__ int wsh[4];
    int c = blockIdx.x * 256 + threadIdx.x;
    int have = (c < G_TOTAL && first[c] != INF_SENTINEL) ? 1 : 0;
    for (int d = 32; d >= 1; d >>= 1) have += __shfl_down(have, d, 64);
    if ((threadIdx.x & 63) == 0) wsh[threadIdx.x >> 6] = have;
    __syncthreads();
    if (threadIdx.x == 0)
        atomicAdd(dcount, wsh[0] + wsh[1] + wsh[2] + wsh[3]);
}

// Guard: if the prefix produced fewer than MAX_VOX distinct cells, the
// prefix bound is insufficient — claim the remaining points too (filtered
// atomicMin; predicate proven safe in round 7). No-op otherwise.
__global__ __launch_bounds__(256) void guard(const float4* __restrict__ pts,
                                             int* __restrict__ first,
                                             const int* __restrict__ dcount,
                                             int K, int n) {
    if (*dcount >= MAX_VOX) return;
    for (int i = K + blockIdx.x * 256 + threadIdx.x; i < n;
         i += gridDim.x * 256) {
        float4 p = pts[i];
        bool ok;
        int c = cell_of(p, ok);
        if (ok && first[c] > i) atomicMin(&first[c], i);
    }
}

// Mark first-point bytes. Distinct cells have distinct first indices, so a
// plain byte store is race-free (byte stores are byte-granular in HW).
__global__ __launch_bounds__(256) void markFirst(const int* __restrict__ first,
                                                 unsigned char* __restrict__ isFirst,
                                                 int n) {
    int c = blockIdx.x * 256 + threadIdx.x;
    if (c >= G_TOTAL) return;
    int f = first[c];
    if (f >= 0 && f < n) isFirst[f] = 1;
}

// Scan A: pack isFirst bytes -> bits[], per-word intra-block exclusive prefix
// (wordLocal) and per-block sums. One thread per 64-bit word, 256 words/block.
__global__ __launch_bounds__(256) void kScanA(const u64* __restrict__ isFirst64,
                                              u64* __restrict__ bits,
                                              unsigned* __restrict__ wordLocal,
                                              int* __restrict__ sums, int W) {
    __shared__ int wsum[4], wexc[4];
    int t = threadIdx.x;
    int wi = blockIdx.x * 256 + t;
    u64 mask = 0;
    if (wi < W) {
        const u64* src = isFirst64 + (size_t)wi * 8;
#pragma unroll
        for (int j = 0; j < 8; j++) {
            u64 chunk = src[j];  // 8 bytes, each 0 or 1
            u64 m8 = (chunk * 0x0102040810204080ull) >> 56;  // gather LSBs
            mask |= m8 << (8 * j);
        }
        bits[wi] = mask;
    }
    int v = __popcll(mask);
    int lane = t & 63, w = t >> 6;
    int x = v;
    for (int d = 1; d < 64; d <<= 1) {
        int y = __shfl_up(x, d, 64);
        if (lane >= d) x += y;
    }
    if (lane == 63) wsum[w] = x;
    __syncthreads();
    if (t == 0) {
        int a = 0;
        for (int j = 0; j < 4; j++) { wexc[j] = a; a += wsum[j]; }
        sums[blockIdx.x] = a;
    }
    __syncthreads();
    if (wi < W) wordLocal[wi] = (unsigned)(wexc[w] + x - v);
}

// Scan B: exclusive scan of per-block sums (nb <= 128); writes num_voxels.
__global__ __launch_bounds__(128) void kScanB(int* __restrict__ sums, int nb,
                                              float* __restrict__ nvOut) {
    __shared__ int wsum[2], wexc[2];
    int t = threadIdx.x;
    int v = (t < nb) ? sums[t] : 0;
    int lane = t & 63, w = t >> 6;
    int x = v;
    for (int d = 1; d < 64; d <<= 1) {
        int y = __shfl_up(x, d, 64);
        if (lane >= d) x += y;
    }
    if (lane == 63) wsum[w] = x;
    __syncthreads();
    if (t == 0) {
        int a = 0;
        for (int j = 0; j < 2; j++) { wexc[j] = a; a += wsum[j]; }
        nvOut[0] = (float)(a < MAX_VOX ? a : MAX_VOX);
    }
    __syncthreads();
    if (t < nb) sums[t] = wexc[w] + x - v;
}

// Rank cells: O(1) per cell — block base + intra-block word prefix + bit pop.
__global__ __launch_bounds__(256) void rankCells(const int* __restrict__ first,
                                                 const u64* __restrict__ bits,
                                                 const unsigned* __restrict__ wordLocal,
                                                 const int* __restrict__ sumsExcl,
                                                 int* __restrict__ rank,
                                                 int* __restrict__ cellOfRank, int n) {
    int c = blockIdx.x * 256 + threadIdx.x;
    if (c >= G_TOTAL) return;
    int f = first[c];
    if (f < 0 || f >= n) return;
    int wf = f >> 6;
    int b = f & 63;
    u64 lowmask = (b == 0) ? 0ull : ((~0ull) >> (64 - b));
    int vr = sumsExcl[wf >> 8] + (int)wordLocal[wf] + __popcll(bits[wf] & lowmask);
    rank[c] = vr;
    if (vr < MAX_VOX) cellOfRank[vr] = c;
}

// Pass 5: append point indices into kept voxels' lists.
// vcount starts at -1; atomicAdd returns old, pos = old+1.
// rank[] is INF for cells never ranked (first >= K path), filtering them.
__global__ __launch_bounds__(256) void pass5(const int* __restrict__ lin,
                                             const int* __restrict__ rank,
                                             int* __restrict__ vcount,
                                             int* __restrict__ list, int n) {
    int i = blockIdx.x * 256 + threadIdx.x;
    if (i >= n) return;
    int c = lin[i];
    if (c < 0) return;
    int vr = rank[c];
    if (vr >= MAX_VOX) return;
    int pos = atomicAdd(&vcount[vr], 1) + 1;
    if (pos < CAP) list[vr * CAP + pos] = i;
}

// Pass F: 4 voxels per 256-thread block (one wave each). Counting-sort the
// collected indices (LDS broadcast reads), write all 32 slots + num_points
// + coors (so no d_out pre-memset is needed).
__global__ __launch_bounds__(256) void passF(const float4* __restrict__ pts,
                                             const int* __restrict__ vcount,
                                             const int* __restrict__ cellOfRank,
                                             const int* __restrict__ list,
                                             float4* __restrict__ voxOut,
                                             float* __restrict__ coorsOut,
                                             float* __restrict__ npOut) {
    __shared__ int s[4][CAP];
    __shared__ int slotPt[4][MAX_PTS];
    int w = threadIdx.x >> 6, lane = threadIdx.x & 63;
    int v = blockIdx.x * 4 + w;
    int cnt = vcount[v] + 1;
    int m = cnt < CAP ? cnt : CAP;
    s[w][lane] = (lane < m) ? list[v * CAP + lane] : 0x7FFFFFFF;
    if (lane < MAX_PTS) slotPt[w][lane] = -1;
    __syncthreads();
    int my = s[w][lane];
    int r = 0;
#pragma unroll
    for (int j = 0; j < CAP; j++) r += (s[w][j] < my) ? 1 : 0;  // broadcast
    if (lane < m && r < MAX_PTS) slotPt[w][r] = my;
    __syncthreads();
    if (lane < MAX_PTS) {
        int p = slotPt[w][lane];
        float4 val = make_float4(0.f, 0.f, 0.f, 0.f);
        if (p >= 0) val = pts[p];
        voxOut[(size_t)v * MAX_PTS + lane] = val;
    }
    if (lane == 0) {
        npOut[v] = (float)(cnt < MAX_PTS ? cnt : MAX_PTS);
        int cell = cellOfRank[v];
        if (cell < 0) {
            coorsOut[3 * v + 0] = -1.0f;
            coorsOut[3 * v + 1] = -1.0f;
            coorsOut[3 * v + 2] = -1.0f;
        } else {
            coorsOut[3 * v + 0] = 0.0f;  // cz (GZ==1)
            coorsOut[3 * v + 1] = (float)(cell / GX);
            coorsOut[3 * v + 2] = (float)(cell % GX);
        }
    }
}

extern "C" void kernel_launch(void* const* d_in, const int* in_sizes, int n_in,
                              void* d_out, int out_size, void* d_ws, size_t ws_size,
                              hipStream_t stream) {
    const float4* pts = (const float4*)d_in[0];
    int n = in_sizes[0] / 4;  // 2,000,000
    int W = (n + 63) >> 6;    // 31250 bitmap words
    int K = PREFIX_K < n ? PREFIX_K : n;

    char* ws = (char*)d_ws;
    size_t off = 0;
    auto alloc = [&](size_t bytes) -> void* {
        void* p = (void*)(ws + off);
        off = (off + bytes + 255) & ~(size_t)255;
        return p;
    };
    int* first = (int*)alloc((size_t)G_TOTAL * 4);
    int* lin = (int*)alloc((size_t)n * 4);
    u64* isFirst64 = (u64*)alloc((size_t)W * 8 * 8);     // W*64 bytes
    u64* bits = (u64*)alloc((size_t)W * 8);
    unsigned* wordLocal = (unsigned*)alloc((size_t)W * 4);
    int* sums = (int*)alloc(128 * 4);
    int* rank = (int*)alloc((size_t)G_TOTAL * 4);
    int* vcount = (int*)alloc((size_t)MAX_VOX * 4);
    int* cellOfRank = (int*)alloc((size_t)MAX_VOX * 4);
    int* dcount = (int*)alloc(256 * 4);
    int* list = (int*)alloc((size_t)MAX_VOX * CAP * 4);
    (void)ws_size;
    (void)n_in;
    (void)out_size;

    float* out = (float*)d_out;
    float4* voxOut = (float4*)out;                          // 20000*32*4
    float* coorsOut = out + (size_t)MAX_VOX * MAX_PTS * 4;  // 20000*3
    float* npOut = coorsOut + (size_t)MAX_VOX * 3;          // 20000
    float* nvOut = npOut + MAX_VOX;                         // 1

    hipMemsetAsync(first, 0x7F, (size_t)G_TOTAL * 4, stream);  // INF

    int nbP = (n + 255) / 256;        // 7813
    int nbC = (G_TOTAL + 255) / 256;  // 837
    int nbW = (W + 255) / 256;        // 123

    pass1<<<nbP, 256, 0, stream>>>(pts, lin, first, isFirst64, vcount,
                                   cellOfRank, rank, dcount, W, K, n);
    countD<<<nbC, 256, 0, stream>>>(first, dcount);
    guard<<<1024, 256, 0, stream>>>(pts, first, dcount, K, n);
    markFirst<<<nbC, 256, 0, stream>>>(first, (unsigned char*)isFirst64, n);
    kScanA<<<nbW, 256, 0, stream>>>(isFirst64, bits, wordLocal, sums, W);
    kScanB<<<1, 128, 0, stream>>>(sums, nbW, nvOut);
    rankCells<<<nbC, 256, 0, stream>>>(first, bits, wordLocal, sums, rank,
                                       cellOfRank, n);
    pass5<<<nbP, 256, 0, stream>>>(lin, rank, vcount, list, n);
    passF<<<MAX_VOX / 4, 256, 0, stream>>>(pts, vcount, cellOfRank, list,
                                           voxOut, coorsOut, npOut);
}